// Round 1
// baseline (278.149 us; speedup 1.0000x reference)
//
#include <hip/hip_runtime.h>

// Problem constants: B=16, S=4096, H=768, T=2000
#define BB 16
#define SS 4096
#define HH 768
#define TT 2000
#define HV (HH / 4)          // 192 float4 per row
#define TPB 16               // tokens per block (4 waves x 4 tokens)
#define BPB (TT / TPB)       // 125 blocks per batch (2000 % 16 == 0)

typedef float vf4 __attribute__((ext_vector_type(4)));

// ---------------------------------------------------------------------------
// Kernel 1: per-batch exclusive prefix sum of subtoken_lengths, +1 offset,
// packed as (start << 2) | len  (start <= 4001 fits 12 bits, len in {0,1,2}).
// One block per batch; 250 active threads x 8 lengths = 2000 exact.
// ---------------------------------------------------------------------------
__global__ __launch_bounds__(256) void tokrep_scan_kernel(
    const int4* __restrict__ lens4, int* __restrict__ packed) {
    __shared__ int sums[256];
    const int b = blockIdx.x;
    const int tid = threadIdx.x;

    int L[8];
    int v[8];
    int s = 0;
    if (tid < 250) {
        int4 a = lens4[b * 500 + tid * 2];
        int4 c = lens4[b * 500 + tid * 2 + 1];
        L[0] = a.x; L[1] = a.y; L[2] = a.z; L[3] = a.w;
        L[4] = c.x; L[5] = c.y; L[6] = c.z; L[7] = c.w;
#pragma unroll
        for (int i = 0; i < 8; ++i) { v[i] = s; s += L[i]; }
    }
    sums[tid] = s;
    __syncthreads();

    // Hillis-Steele inclusive scan over the 256 chunk sums
    for (int off = 1; off < 256; off <<= 1) {
        int x = (tid >= off) ? sums[tid - off] : 0;
        __syncthreads();
        if (tid >= off) sums[tid] += x;
        __syncthreads();
    }

    if (tid < 250) {
        const int base = 1 + ((tid == 0) ? 0 : sums[tid - 1]);
        int4 o0 = make_int4(((base + v[0]) << 2) | L[0],
                            ((base + v[1]) << 2) | L[1],
                            ((base + v[2]) << 2) | L[2],
                            ((base + v[3]) << 2) | L[3]);
        int4 o1 = make_int4(((base + v[4]) << 2) | L[4],
                            ((base + v[5]) << 2) | L[5],
                            ((base + v[6]) << 2) | L[6],
                            ((base + v[7]) << 2) | L[7]);
        int4* p4 = (int4*)(packed + b * TT);   // 16B aligned (b*8000 bytes)
        p4[tid * 2]     = o0;
        p4[tid * 2 + 1] = o1;
    }
}

// ---------------------------------------------------------------------------
// Kernel 2: pooled[b,t,:] = len==0 ? 0 : mean(hidden[b, start:start+len, :])
// One 64-lane wave owns one full token row: lane l covers float4 slots
// {l, l+64, l+128}. Each wave handles 4 consecutive tokens (one int4 of
// packed metadata, readfirstlane'd -> scalar branches, saddr-form loads).
// Block = 256 threads = 4 waves = 16 tokens; grid = 2000 blocks -> 8000
// waves = 31.25 waves/CU, fully resident in a single pass.
// ---------------------------------------------------------------------------
__global__ __launch_bounds__(256, 8) void tokrep_pool_kernel(
    const vf4* __restrict__ hs, const int* __restrict__ packed,
    vf4* __restrict__ out) {
    const int wave = threadIdx.x >> 6;
    const int lane = threadIdx.x & 63;
    const int b    = blockIdx.x / BPB;                 // const div -> magic mul
    const int t0   = (blockIdx.x - b * BPB) * TPB;
    const int bt0  = b * TT + t0 + wave * 4;           // this wave's 4 tokens

    // One 16B broadcast load fetches (start,len) for all 4 tokens.
    const int4 pk4 = *(const int4*)(packed + bt0);
    const int pk[4] = {pk4.x, pk4.y, pk4.z, pk4.w};

    const vf4* __restrict__ hb = hs + (size_t)b * (SS * HV);
    vf4* __restrict__ ob = out + (size_t)bt0 * HV + lane;

#pragma unroll
    for (int it = 0; it < 4; ++it) {
        const int p     = __builtin_amdgcn_readfirstlane(pk[it]);
        const int len   = p & 3;
        const int start = p >> 2;
        const vf4* row  = hb + (size_t)start * HV + lane;

        vf4 r0 = (vf4)(0.f), r1 = (vf4)(0.f), r2 = (vf4)(0.f);
        if (len != 0) {
            r0 = __builtin_nontemporal_load(row);
            r1 = __builtin_nontemporal_load(row + 64);
            r2 = __builtin_nontemporal_load(row + 128);
            if (len == 2) {
                vf4 s0 = __builtin_nontemporal_load(row + HV);
                vf4 s1 = __builtin_nontemporal_load(row + HV + 64);
                vf4 s2 = __builtin_nontemporal_load(row + HV + 128);
                r0 = (r0 + s0) * 0.5f;
                r1 = (r1 + s1) * 0.5f;
                r2 = (r2 + s2) * 0.5f;
            }
        }
        vf4* o = ob + it * HV;
        __builtin_nontemporal_store(r0, o);
        __builtin_nontemporal_store(r1, o + 64);
        __builtin_nontemporal_store(r2, o + 128);
    }
}

// ---------------------------------------------------------------------------
extern "C" void kernel_launch(void* const* d_in, const int* in_sizes, int n_in,
                              void* d_out, int out_size, void* d_ws, size_t ws_size,
                              hipStream_t stream) {
    const float* hs = (const float*)d_in[0];   // (B,S,H) fp32
    const int* lens = (const int*)d_in[1];     // (B,T) int32
    float* out      = (float*)d_out;           // (B,T,H) fp32
    int* packed     = (int*)d_ws;              // B*T ints = 128 KB scratch

    tokrep_scan_kernel<<<BB, 256, 0, stream>>>((const int4*)lens, packed);

    tokrep_pool_kernel<<<(BB * TT) / TPB, 256, 0, stream>>>(
        (const vf4*)hs, packed, (vf4*)out);
}